// Round 4
// baseline (522.390 us; speedup 1.0000x reference)
//
#include <hip/hip_runtime.h>
#include <math.h>

constexpr int NPIX  = 262144;   // 512*512
constexpr int NLAB  = 8;
constexpr int NITER = 5;        // Newton-Schulz iterations

// ---------------- workspace layout (4B-element offsets), runtime nblk ----------------
__host__ __device__ inline size_t offMpart()         { return 0; }
__host__ __device__ inline size_t offSpart(int nblk) { return (size_t)2*nblk*8*4096; }
__host__ __device__ inline size_t offCnt(int nblk)   { return offSpart(nblk) + (size_t)2*nblk*8*64; }
__host__ __device__ inline size_t offMR(int nblk)    { return offCnt(nblk) + (size_t)2*nblk*8; }
__host__ __device__ inline size_t offSR(int nblk)    { return offMR(nblk) + 2*8*4096; }
__host__ __device__ inline size_t offCR(int nblk)    { return offSR(nblk) + 2*8*64; }
__host__ __device__ inline size_t offWH(int nblk)    { return offCR(nblk) + 16; }
__host__ __device__ inline size_t offCO(int nblk)    { return offWH(nblk) + 8*4096; }
__host__ __device__ inline size_t offT(int nblk)     { return offCO(nblk) + 8*4096; }
__host__ __device__ inline size_t offBIAS(int nblk)  { return offT(nblk) + 8*4096; }
__host__ __device__ inline size_t offMUC(int nblk)   { return offBIAS(nblk) + 8*64; }
__host__ __device__ inline size_t offMUS(int nblk)   { return offMUC(nblk) + 8*64; }
__host__ __device__ inline size_t offVALID(int nblk) { return offMUS(nblk) + 8*64; }
__host__ __device__ inline size_t offEnd(int nblk)   { return offVALID(nblk) + 8; }

// =====================================================================
// K1: single-pass per-label moments (unchanged from round 2).
// =====================================================================
__global__ __launch_bounds__(512, 2) void k_moments(
    const float* __restrict__ cont, const float* __restrict__ styl,
    const int* __restrict__ cseg, const int* __restrict__ sseg,
    float* __restrict__ ws, int nblk)
{
  const int t = blockIdx.y, blk = blockIdx.x;
  const float* __restrict__ X  = t ? styl : cont;
  const int*  __restrict__ seg = t ? sseg : cseg;
  const int tid = threadIdx.x, lane = tid & 63, wv = tid >> 6;

  __shared__ float xs[256 * 64];   // exactly 64 KB

  const int r0 = (lane >> 3) << 3;
  const int c0 = (lane & 7) << 3;

  float acc[8][8];
  #pragma unroll
  for (int i = 0; i < 8; ++i)
    #pragma unroll
    for (int j = 0; j < 8; ++j) acc[i][j] = 0.f;
  float ssum = 0.f;
  int   cnt  = 0;

  const int chunk = NPIX / nblk;
  const int pbase = blk * chunk;
  const int nph   = chunk >> 8;
  const int ci  = tid >> 5;
  const int pxi = (tid & 31) << 2;
  const int swW = (tid & 7) << 2;

  for (int ph = 0; ph < nph; ++ph) {
    const int p0 = pbase + (ph << 8);
    float4 v[8];
    #pragma unroll
    for (int q = 0; q < 8; ++q) {
      const int c  = ci + ((q & 3) << 4);
      const int px = pxi + ((q >> 2) << 7);
      v[q] = *reinterpret_cast<const float4*>(&X[(size_t)c * NPIX + p0 + px]);
    }
    int lb[4];
    #pragma unroll
    for (int g = 0; g < 4; ++g) lb[g] = seg[p0 + (g << 6) + lane];

    __syncthreads();
    #pragma unroll
    for (int q = 0; q < 8; ++q) {
      const int c  = ci + ((q & 3) << 4);
      const int px = pxi + ((q >> 2) << 7);
      const int pc = c ^ swW;
      xs[(px + 0) * 64 + pc] = v[q].x;
      xs[(px + 1) * 64 + pc] = v[q].y;
      xs[(px + 2) * 64 + pc] = v[q].z;
      xs[(px + 3) * 64 + pc] = v[q].w;
    }
    __syncthreads();

    for (int g = 0; g < 4; ++g) {
      unsigned long long m = __ballot(lb[g] == wv);
      cnt += __popcll(m);
      while (m) {
        const int j = (g << 6) + __builtin_ctzll(m);
        m &= m - 1;
        const int sw = j & 28;
        const float4 a0 = *reinterpret_cast<const float4*>(&xs[j * 64 + (r0 ^ sw)]);
        const float4 a1 = *reinterpret_cast<const float4*>(&xs[j * 64 + ((r0 ^ sw) ^ 4)]);
        const float4 b0 = *reinterpret_cast<const float4*>(&xs[j * 64 + (c0 ^ sw)]);
        const float4 b1 = *reinterpret_cast<const float4*>(&xs[j * 64 + ((c0 ^ sw) ^ 4)]);
        ssum += xs[j * 64 + (lane ^ sw)];
        const float av[8] = {a0.x, a0.y, a0.z, a0.w, a1.x, a1.y, a1.z, a1.w};
        const float bv[8] = {b0.x, b0.y, b0.z, b0.w, b1.x, b1.y, b1.z, b1.w};
        #pragma unroll
        for (int i = 0; i < 8; ++i)
          #pragma unroll
          for (int jj = 0; jj < 8; ++jj) acc[i][jj] += av[i] * bv[jj];
      }
    }
  }

  float* Md = ws + offMpart() + (size_t)((t * nblk + blk) * 8 + wv) * 4096;
  #pragma unroll
  for (int i = 0; i < 8; ++i) {
    *reinterpret_cast<float4*>(&Md[(r0 + i) * 64 + c0]) =
        make_float4(acc[i][0], acc[i][1], acc[i][2], acc[i][3]);
    *reinterpret_cast<float4*>(&Md[(r0 + i) * 64 + c0 + 4]) =
        make_float4(acc[i][4], acc[i][5], acc[i][6], acc[i][7]);
  }
  ws[offSpart(nblk) + (size_t)((t * nblk + blk) * 8 + wv) * 64 + lane] = ssum;
  if (lane == 0) ws[offCnt(nblk) + (size_t)(t * nblk + blk) * 8 + wv] = (float)cnt;
}

// =====================================================================
// K1b: reduce partials over nblk (unchanged).
// =====================================================================
__global__ __launch_bounds__(256) void k_reduce(float* __restrict__ ws, int nblk)
{
  const int b = blockIdx.x;
  const int sgm = b & 15, tl = b >> 4, l = tl & 7, t = tl >> 3;
  const int tid = threadIdx.x;
  const size_t stride = (size_t)8 * 4096;
  const float* src = ws + offMpart() + (size_t)(t * nblk) * stride + (size_t)l * 4096 + sgm * 256 + tid;
  float s = 0.f;
  for (int bb = 0; bb < nblk; ++bb) s += src[bb * stride];
  ws[offMR(nblk) + (size_t)tl * 4096 + sgm * 256 + tid] = s;
  if (sgm == 0) {
    if (tid < 64) {
      float q = 0.f;
      for (int bb = 0; bb < nblk; ++bb)
        q += ws[offSpart(nblk) + (size_t)((t * nblk + bb) * 8 + l) * 64 + tid];
      ws[offSR(nblk) + tl * 64 + tid] = q;
    } else if (tid == 64) {
      float q = 0.f;
      for (int bb = 0; bb < nblk; ++bb)
        q += ws[offCnt(nblk) + (size_t)(t * nblk + bb) * 8 + l];
      ws[offCR(nblk) + tl] = q;
    }
  }
}

// =====================================================================
// 64x64 symmetric-operand matmul on LDS (unchanged).
// =====================================================================
__device__ __forceinline__ void mm64s4(float* __restrict__ dst,
    const float* __restrict__ A, const float* __restrict__ B,
    int tid, float p0, float p1)
{
  const int lane = tid & 63, wv = tid >> 6;
  const int r0 = (wv << 4) + ((lane >> 4) << 2);
  const int c0 = (lane & 15) << 2;
  float acc[4][4];
  #pragma unroll
  for (int i = 0; i < 4; ++i)
    #pragma unroll
    for (int j = 0; j < 4; ++j) acc[i][j] = 0.f;
  #pragma unroll 4
  for (int k = 0; k < 64; ++k) {
    const float4 a = *reinterpret_cast<const float4*>(&A[k * 64 + r0]);
    const float4 b = *reinterpret_cast<const float4*>(&B[k * 64 + c0]);
    const float av[4] = {a.x, a.y, a.z, a.w};
    const float bv[4] = {b.x, b.y, b.z, b.w};
    #pragma unroll
    for (int i = 0; i < 4; ++i)
      #pragma unroll
      for (int j = 0; j < 4; ++j) acc[i][j] += av[i] * bv[j];
  }
  #pragma unroll
  for (int i = 0; i < 4; ++i) {
    float4 o;
    o.x = p1 * acc[i][0] + (((r0 + i) == (c0 + 0)) ? p0 : 0.f);
    o.y = p1 * acc[i][1] + (((r0 + i) == (c0 + 1)) ? p0 : 0.f);
    o.z = p1 * acc[i][2] + (((r0 + i) == (c0 + 2)) ? p0 : 0.f);
    o.w = p1 * acc[i][3] + (((r0 + i) == (c0 + 3)) ? p0 : 0.f);
    *reinterpret_cast<float4*>(&dst[(r0 + i) * 64 + c0]) = o;
  }
}

// =====================================================================
// K2: cov build + coupled Newton-Schulz; final iteration computes only
// the needed product (unchanged from round 3).
// =====================================================================
__global__ __launch_bounds__(256) void k_ns(float* __restrict__ ws, int nblk)
{
  const int l = blockIdx.x & 7, t = blockIdx.x >> 3;
  const int tid = threadIdx.x;
  __shared__ float bA[4096], bY[4096], bZ[4096], bT[4096];
  float* svec   = bT;
  float* rowsum = bT + 64;
  float* scal   = bT + 128;

  const float n0 = ws[offCR(nblk) + l];
  const float n1 = ws[offCR(nblk) + 8 + l];
  const float n = t ? n1 : n0;
  const bool valid = (n0 > 10.f) && (n1 > 10.f) && (n0 < 100.f * n1) && (n1 < 100.f * n0);
  if (tid < 64) svec[tid] = ws[offSR(nblk) + (t * 8 + l) * 64 + tid];
  __syncthreads();

  const float invn = 1.f / fmaxf(n, 1.f);
  const float nm1  = n - 1.f;
  const float rdiv = 1.f / ((nm1 == 0.f) ? 1e-5f : nm1);
  const int i0 = tid >> 2, jb = (tid & 3) << 4;
  const float Si = svec[i0];
  const float* MRp = ws + offMR(nblk) + (size_t)(t * 8 + l) * 4096;
  #pragma unroll
  for (int q = 0; q < 4; ++q) {
    const int j = jb + (q << 2);
    const float4 m  = *reinterpret_cast<const float4*>(&MRp[i0 * 64 + j]);
    const float4 sj = *reinterpret_cast<const float4*>(&svec[j]);
    float4 a;
    a.x = (m.x - Si * sj.x * invn) * rdiv + ((t == 0 && i0 == j + 0) ? 1.f : 0.f);
    a.y = (m.y - Si * sj.y * invn) * rdiv + ((t == 0 && i0 == j + 1) ? 1.f : 0.f);
    a.z = (m.z - Si * sj.z * invn) * rdiv + ((t == 0 && i0 == j + 2) ? 1.f : 0.f);
    a.w = (m.w - Si * sj.w * invn) * rdiv + ((t == 0 && i0 == j + 3) ? 1.f : 0.f);
    *reinterpret_cast<float4*>(&bA[i0 * 64 + j]) = a;
  }
  if (tid < 64) ws[(t ? offMUS(nblk) : offMUC(nblk)) + l * 64 + tid] = svec[tid] * invn;
  if (t == 0 && tid == 0) ws[offVALID(nblk) + l] = valid ? 1.f : 0.f;
  __syncthreads();

  if (tid < 64) {
    float s = 0.f;
    for (int j = 0; j < 64; ++j) s += fabsf(bA[j * 64 + tid]);
    rowsum[tid] = s;
  }
  __syncthreads();
  if (tid == 0) {
    float c = 0.f;
    for (int i = 0; i < 64; ++i) c = fmaxf(c, rowsum[i]);
    scal[0] = fmaxf(c, 1e-20f);
  }
  __syncthreads();
  const float cval = scal[0];
  const float rc = 1.f / cval;
  __syncthreads();

  #pragma unroll
  for (int q = 0; q < 4; ++q) {
    const int j = jb + (q << 2);
    float4 a = *reinterpret_cast<const float4*>(&bA[i0 * 64 + j]);
    a.x *= rc; a.y *= rc; a.z *= rc; a.w *= rc;
    *reinterpret_cast<float4*>(&bY[i0 * 64 + j]) = a;
    float4 z;
    z.x = (i0 == j + 0) ? 1.f : 0.f; z.y = (i0 == j + 1) ? 1.f : 0.f;
    z.z = (i0 == j + 2) ? 1.f : 0.f; z.w = (i0 == j + 3) ? 1.f : 0.f;
    *reinterpret_cast<float4*>(&bZ[i0 * 64 + j]) = z;
  }
  __syncthreads();

  float *Y = bY, *Z = bZ, *T = bT, *Wb = bA;
  for (int it = 0; it < NITER - 1; ++it) {
    mm64s4(T, Z, Y, tid, 1.5f, -0.5f); __syncthreads();
    mm64s4(Wb, Y, T, tid, 0.f, 1.f);   __syncthreads();
    mm64s4(Y, T, Z, tid, 0.f, 1.f);    __syncthreads();
    float* nz = Y; Y = Wb; Wb = Z; Z = nz;
  }
  mm64s4(T, Z, Y, tid, 1.5f, -0.5f); __syncthreads();
  if (t) mm64s4(Wb, Y, T, tid, 0.f, 1.f);   // Y_final
  else   mm64s4(Wb, T, Z, tid, 0.f, 1.f);   // Z_final
  __syncthreads();

  const float osc = t ? sqrtf(cval) : (1.0f / sqrtf(cval));
  float* dst = ws + (t ? offCO(nblk) : offWH(nblk)) + (size_t)l * 4096;
  #pragma unroll
  for (int q = 0; q < 4; ++q) {
    const int j = jb + (q << 2);
    float4 v = *reinterpret_cast<const float4*>(&Wb[i0 * 64 + j]);
    v.x *= osc; v.y *= osc; v.z *= osc; v.w *= osc;
    *reinterpret_cast<float4*>(&dst[i0 * 64 + j]) = v;
  }
}

// =====================================================================
// K2b: T_l = CO_l @ WH_l (identity if invalid), bias = mus - T@muc (0 if invalid)
// =====================================================================
__global__ __launch_bounds__(256) void k_tmat(float* __restrict__ ws, int nblk)
{
  const int l = blockIdx.x;
  const int tid = threadIdx.x;
  __shared__ float Am[4096], Bm[4096];
  __shared__ float red[64];
  __shared__ float mucS[64], musS[64];
  const bool valid = ws[offVALID(nblk) + l] > 0.5f;
  if (tid < 64) {
    red[tid] = 0.f;
    mucS[tid] = ws[offMUC(nblk) + l * 64 + tid];
    musS[tid] = ws[offMUS(nblk) + l * 64 + tid];
  }
  #pragma unroll
  for (int q = 0; q < 4; ++q) {
    const int e = tid * 4 + q * 1024;
    *reinterpret_cast<float4*>(&Am[e]) =
        *reinterpret_cast<const float4*>(&ws[offCO(nblk) + (size_t)l * 4096 + e]);
    *reinterpret_cast<float4*>(&Bm[e]) =
        *reinterpret_cast<const float4*>(&ws[offWH(nblk) + (size_t)l * 4096 + e]);
  }
  __syncthreads();
  const int lane = tid & 63, wv = tid >> 6;
  const int r0 = (wv << 4) + ((lane >> 4) << 2);
  const int c0 = (lane & 15) << 2;
  float acc[4][4];
  #pragma unroll
  for (int i = 0; i < 4; ++i)
    #pragma unroll
    for (int j = 0; j < 4; ++j) acc[i][j] = 0.f;
  #pragma unroll 4
  for (int k = 0; k < 64; ++k) {
    const float4 a = *reinterpret_cast<const float4*>(&Am[k * 64 + r0]);
    const float4 b = *reinterpret_cast<const float4*>(&Bm[k * 64 + c0]);
    const float av[4] = {a.x, a.y, a.z, a.w};
    const float bv[4] = {b.x, b.y, b.z, b.w};
    #pragma unroll
    for (int i = 0; i < 4; ++i)
      #pragma unroll
      for (int j = 0; j < 4; ++j) acc[i][j] += av[i] * bv[j];
  }
  float* Td = ws + offT(nblk) + (size_t)l * 4096;
  #pragma unroll
  for (int i = 0; i < 4; ++i) {
    float4 o;
    o.x = valid ? acc[i][0] : (((r0 + i) == (c0 + 0)) ? 1.f : 0.f);
    o.y = valid ? acc[i][1] : (((r0 + i) == (c0 + 1)) ? 1.f : 0.f);
    o.z = valid ? acc[i][2] : (((r0 + i) == (c0 + 2)) ? 1.f : 0.f);
    o.w = valid ? acc[i][3] : (((r0 + i) == (c0 + 3)) ? 1.f : 0.f);
    *reinterpret_cast<float4*>(&Td[(r0 + i) * 64 + c0]) = o;
    const float bp = o.x * mucS[c0] + o.y * mucS[c0 + 1] + o.z * mucS[c0 + 2] + o.w * mucS[c0 + 3];
    atomicAdd(&red[r0 + i], bp);
  }
  __syncthreads();
  if (tid < 64) ws[offBIAS(nblk) + l * 64 + tid] = valid ? (musS[tid] - red[tid]) : 0.f;
}

// =====================================================================
// K3: apply y = T_lab x + bias_lab.  1024-px window per block (512 thr,
// 8 waves).  Block-LOCAL counting sort by label in LDS (keeps all global
// I/O within the window -> no line-level overfetch, unlike the round-3
// global sort), label runs padded to multiples of 64 so every 64-px
// group is wave-uniform -> T/bias via scalar loads (SMEM pipe), x in 64
// VGPRs, zero LDS in the hot loop.  ngrp <= 23, wave w takes g = w, w+8, ...
// =====================================================================
__global__ __launch_bounds__(512) void k_apply(
    const float* __restrict__ cont, const int* __restrict__ cseg,
    const float* __restrict__ ws, float* __restrict__ out, int nblk)
{
  const int tid = threadIdx.x, lane = tid & 63, wv = tid >> 6;
  const int base = blockIdx.x << 10;

  __shared__ unsigned short sidx[1536];
  __shared__ int chcnt[16][8];
  __shared__ int curs[16][8];
  __shared__ int offp[9];
  __shared__ int grpl[24];
  __shared__ int ngrpS;

  // --- label read + per-chunk (64-px) per-label counts via ballot ---
  int lb[2];
  #pragma unroll
  for (int s = 0; s < 2; ++s) {
    lb[s] = cseg[base + (s << 9) + tid];
    const int chunk = (s << 3) + wv;
    #pragma unroll
    for (int l = 0; l < 8; ++l) {
      unsigned long long m = __ballot(lb[s] == l);
      if (lane == 0) chcnt[chunk][l] = __popcll(m);
    }
  }
  __syncthreads();
  if (tid == 0) {
    int off = 0;
    for (int l = 0; l < 8; ++l) {
      offp[l] = off;
      int c = 0;
      for (int ch = 0; ch < 16; ++ch) c += chcnt[ch][l];
      off += (c + 63) & ~63;        // pad each label run to x64
    }
    offp[8] = off;
    ngrpS = off >> 6;
  }
  __syncthreads();
  if (tid < 128) {                   // per-chunk write cursors
    const int ch = tid >> 3, l = tid & 7;
    int w = offp[l];
    for (int c2 = 0; c2 < ch; ++c2) w += chcnt[c2][l];
    curs[ch][l] = w;
  }
  __syncthreads();
  const unsigned long long mlt = (1ull << lane) - 1ull;
  #pragma unroll
  for (int s = 0; s < 2; ++s) {      // stable scatter
    const int chunk = (s << 3) + wv;
    const int myl = lb[s];
    int rank = 0;
    #pragma unroll
    for (int l = 0; l < 8; ++l) {
      unsigned long long m = __ballot(myl == l);
      if (l == myl) rank = __popcll(m & mlt);
    }
    sidx[curs[chunk][myl] + rank] = (unsigned short)((s << 9) + tid);
  }
  __syncthreads();
  if (tid < 8) {                     // duplicate-pad tails (benign re-stores)
    int c = 0;
    for (int ch = 0; ch < 16; ++ch) c += chcnt[ch][tid];
    if (c > 0) {
      const unsigned short f = sidx[offp[tid]];
      for (int i = offp[tid] + c; i < offp[tid + 1]; ++i) sidx[i] = f;
    }
  }
  const int ngrp = ngrpS;
  if (tid < 24 && tid < ngrp) {      // group -> label table
    int lab = 0;
    for (int l = 1; l < 8; ++l) lab += ((tid << 6) >= offp[l]) ? 1 : 0;
    grpl[tid] = lab;
  }
  __syncthreads();

  // --- hot loop: wave-uniform label groups ---
  for (int g = wv; g < ngrp; g += 8) {
    const int lab = __builtin_amdgcn_readfirstlane(grpl[g]);
    const int p   = base + sidx[(g << 6) + lane];

    float x[64];
    #pragma unroll
    for (int c = 0; c < 64; ++c) x[c] = cont[(size_t)c * NPIX + p];

    const float* __restrict__ Tb = ws + offT(nblk) + (size_t)lab * 4096;
    const float* __restrict__ Bb = ws + offBIAS(nblk) + (size_t)lab * 64;

    #pragma unroll 2
    for (int oc = 0; oc < 64; ++oc) {
      float a0 = Bb[oc], a1 = 0.f, a2 = 0.f, a3 = 0.f;
      const float* __restrict__ Tr = Tb + oc * 64;
      #pragma unroll
      for (int k4 = 0; k4 < 16; ++k4) {
        const float4 tv = *reinterpret_cast<const float4*>(&Tr[4 * k4]);
        a0 += tv.x * x[4 * k4 + 0];
        a1 += tv.y * x[4 * k4 + 1];
        a2 += tv.z * x[4 * k4 + 2];
        a3 += tv.w * x[4 * k4 + 3];
      }
      out[(size_t)oc * NPIX + p] = (a0 + a1) + (a2 + a3);
    }
  }
}

// =====================================================================
extern "C" void kernel_launch(void* const* d_in, const int* in_sizes, int n_in,
                              void* d_out, int out_size, void* d_ws, size_t ws_size,
                              hipStream_t stream)
{
  const float* cont = (const float*)d_in[0];
  const float* styl = (const float*)d_in[1];
  const int*   cseg = (const int*)d_in[2];
  const int*   sseg = (const int*)d_in[3];
  float*       ws   = (float*)d_ws;
  float*       out  = (float*)d_out;

  const size_t favail = ws_size / 4;
  int nblk = 128;
  while (nblk > 8 && offEnd(nblk) > favail) nblk >>= 1;

  k_moments<<<dim3(nblk, 2), 512, 0, stream>>>(cont, styl, cseg, sseg, ws, nblk);
  k_reduce<<<dim3(256), 256, 0, stream>>>(ws, nblk);
  k_ns<<<dim3(16), 256, 0, stream>>>(ws, nblk);
  k_tmat<<<dim3(8), 256, 0, stream>>>(ws, nblk);
  k_apply<<<dim3(NPIX / 1024), 512, 0, stream>>>(cont, cseg, ws, out, nblk);
}